// Round 1
// baseline (131.206 us; speedup 1.0000x reference)
//
#include <hip/hip_runtime.h>

// Problem dims (compile-time)
#define BATCH 1024
#define NELEC 64
#define DF    32     // backflow feature dim D
#define NION  16
#define NORB  32
#define NE    32     // NELEC / NSPIN
// grid = NSPIN*BATCH = 2048 blocks, 256 threads each

__global__ __launch_bounds__(256) void deq_orbital_kernel(
    const float* __restrict__ x,      // (B, NELEC, D)
    const float* __restrict__ r_ei,   // (B, NELEC, NION, 3)
    const float* __restrict__ W_orb,  // (2, 2D, NORB)
    const float* __restrict__ b_orb,  // (2, NORB)
    const float* __restrict__ W_env,  // (2, NION, 3, NORB, 3)
    const float* __restrict__ w_ion,  // (2, NION)
    float* __restrict__ out)          // (2, B, NE, NE, NORB)
{
    __shared__ float sx[NE][DF];          // 4 KB   x tile
    __shared__ float sworb[2*DF][NORB];   // 8 KB   W_orb (this spin)
    __shared__ float sr[NE][NION*3];      // 6 KB   r_ei tile
    __shared__ float swe[NION*3*NORB*3];  // 18 KB  W_env (this spin)
    __shared__ float sU[NE][NORB];        // 4 KB
    __shared__ float sV[NE][NORB];        // 4 KB   later: (V+b)*env
    __shared__ float sE[NE][NORB];        // 4 KB   env
    __shared__ float sb[NORB];
    __shared__ float swion[NION];

    const int t   = threadIdx.x;
    const int blk = blockIdx.x;
    const int s   = blk >> 10;          // / BATCH
    const int b   = blk & (BATCH - 1);

    // ---------------- stage ----------------
    // x tile: 1024 floats, contiguous
    {
        const float4* xg = (const float4*)(x + (size_t)(b*NELEC + s*NE) * DF);
        ((float4*)&sx[0][0])[t] = xg[t];
    }
    // W_orb for this spin: 2048 floats
    {
        const float4* wg = (const float4*)(W_orb + (size_t)s * 2*DF*NORB);
        float4* d = (float4*)&sworb[0][0];
        d[t]       = wg[t];
        d[t + 256] = wg[t + 256];
    }
    // r_ei tile: 1536 floats, contiguous
    {
        const float4* rg = (const float4*)(r_ei + (size_t)(b*NELEC + s*NE) * NION * 3);
        float4* d = (float4*)&sr[0][0];
        d[t] = rg[t];
        if (t < 128) d[t + 256] = rg[t + 256];
    }
    // W_env for this spin: 4608 floats = 1152 float4
    {
        const float4* weg = (const float4*)(W_env + (size_t)s * NION*3*NORB*3);
        float4* d = (float4*)swe;
        for (int j = t; j < 1152; j += 256) d[j] = weg[j];
    }
    if (t < NORB) sb[t]    = b_orb[s*NORB + t];
    if (t < NION) swion[t] = w_ion[s*NION + t];
    __syncthreads();

    // ---------------- compute U, V (two 32x32x32 GEMMs) ----------------
    const int o  = t & 31;       // orbital, across lanes -> conflict-free LDS
    const int ng = t >> 5;       // electron group 0..7, 4 electrons each
    float u_acc[4], v_acc[4];
    #pragma unroll
    for (int uu = 0; uu < 4; ++uu) { u_acc[uu] = 0.f; v_acc[uu] = 0.f; }
    #pragma unroll
    for (int d = 0; d < DF; ++d) {
        const float w0 = sworb[d][o];        // lanes: consecutive o -> no conflict
        const float w1 = sworb[DF + d][o];
        #pragma unroll
        for (int uu = 0; uu < 4; ++uu) {
            const float xv = sx[ng*4 + uu][d];  // broadcast
            u_acc[uu] += xv * w0;
            v_acc[uu] += xv * w1;
        }
    }
    #pragma unroll
    for (int uu = 0; uu < 4; ++uu) {
        sU[ng*4 + uu][o] = u_acc[uu];
        sV[ng*4 + uu][o] = v_acc[uu];
    }

    // ---------------- envelope ----------------
    // env[n][o] = sum_i exp(-|| sum_d r[n,i,d] * W_env[i,d,o,:] ||) * w_ion[i]
    #pragma unroll
    for (int uu = 0; uu < 4; ++uu) {
        const int n = ng*4 + uu;
        float acc = 0.f;
        #pragma unroll
        for (int i = 0; i < NION; ++i) {
            const float r0 = sr[n][i*3 + 0];   // broadcast
            const float r1 = sr[n][i*3 + 1];
            const float r2 = sr[n][i*3 + 2];
            // swe[((i*3+d)*NORB + o)*3 + e]; stride-3 across o -> 3 coprime 32, no conflict
            const float* wp = &swe[i*3*NORB*3 + o*3];
            const float s0 = r0*wp[0] + r1*wp[NORB*3    ] + r2*wp[2*NORB*3    ];
            const float s1 = r0*wp[1] + r1*wp[NORB*3 + 1] + r2*wp[2*NORB*3 + 1];
            const float s2 = r0*wp[2] + r1*wp[NORB*3 + 2] + r2*wp[2*NORB*3 + 2];
            const float dist = sqrtf(s0*s0 + s1*s1 + s2*s2);
            acc += __expf(-dist) * swion[i];
        }
        sE[n][o] = acc;
        // fold (V + b) * env in place (this thread owns exactly these entries)
        sV[n][o] = (v_acc[uu] + sb[o]) * acc;
    }
    __syncthreads();

    // ---------------- epilogue: out[p,i,o] = U[p,o]*E[i,o] + W1[i,o] ----------------
    // thread t owns (i = t>>3, o0 = (t&7)*4) for ALL p -> E/W1 hoisted to registers
    const int io = t >> 3;
    const int o0 = (t & 7) * 4;
    const float4 e4 = *(const float4*)&sE[io][o0];
    const float4 w4 = *(const float4*)&sV[io][o0];
    float4* outp = (float4*)(out + (size_t)blk * (NE*NE*NORB));
    #pragma unroll
    for (int p = 0; p < NE; ++p) {
        const float4 u4 = *(const float4*)&sU[p][o0];   // broadcast across lanes
        float4 r;
        r.x = u4.x*e4.x + w4.x;
        r.y = u4.y*e4.y + w4.y;
        r.z = u4.z*e4.z + w4.z;
        r.w = u4.w*e4.w + w4.w;
        outp[p*256 + t] = r;   // 256 threads x 16B = 4 KB contiguous per iter
    }
}

extern "C" void kernel_launch(void* const* d_in, const int* in_sizes, int n_in,
                              void* d_out, int out_size, void* d_ws, size_t ws_size,
                              hipStream_t stream) {
    const float* x     = (const float*)d_in[0];
    const float* r_ei  = (const float*)d_in[1];
    const float* W_orb = (const float*)d_in[2];
    const float* b_orb = (const float*)d_in[3];
    const float* W_env = (const float*)d_in[4];
    const float* w_ion = (const float*)d_in[5];
    float* out = (float*)d_out;

    deq_orbital_kernel<<<2048, 256, 0, stream>>>(x, r_ei, W_orb, b_orb, W_env, w_ion, out);
}

// Round 2
// 84.633 us; speedup vs baseline: 1.5503x; 1.5503x over previous
//
#include <hip/hip_runtime.h>

// Problem dims (compile-time)
#define BATCH 1024
#define NELEC 64
#define DF    32     // backflow feature dim D
#define NION  16
#define NORB  32
#define NE    32     // NELEC / NSPIN
#define NSB   2048   // NSPIN * BATCH
#define FACT_FLOATS (NSB * NE * NORB)        // 2M floats = 8 MB per factor
#define WS_NEEDED   ((size_t)3 * FACT_FLOATS * 4)

// ---------------------------------------------------------------------------
// K1: per (s,b) compute the rank-1 factors
//   U[p,o]   = sum_d x[p,d] * W_orb[s, d, o]
//   V[i,o]   = sum_d x[i,d] * W_orb[s, D+d, o]
//   E[i,o]   = sum_ion exp(-||W_env (r_i - R_ion)||) * w_ion
//   W[i,o]   = (V[i,o] + b[o]) * E[i,o]
// out[p,i,o] = U[p,o] * E[i,o] + W[i,o]   (done by K2)
// ---------------------------------------------------------------------------
__global__ __launch_bounds__(256) void k1_factors(
    const float* __restrict__ x,      // (B, NELEC, D)
    const float* __restrict__ r_ei,   // (B, NELEC, NION, 3)
    const float* __restrict__ W_orb,  // (2, 2D, NORB)
    const float* __restrict__ b_orb,  // (2, NORB)
    const float* __restrict__ W_env,  // (2, NION, 3, NORB, 3)
    const float* __restrict__ w_ion,  // (2, NION)
    float* __restrict__ Uf,           // (NSB, NE, NORB)
    float* __restrict__ Ef,
    float* __restrict__ Wf)
{
    __shared__ float sx[NE][DF];          // 4 KB
    __shared__ float sworb[2*DF][NORB];   // 8 KB
    __shared__ float sr[NE][NION*3];      // 6 KB
    __shared__ float swe[NION*3*NORB*3];  // 18 KB
    __shared__ float sb[NORB];
    __shared__ float swion[NION];

    const int t   = threadIdx.x;
    const int blk = blockIdx.x;
    const int s   = blk >> 10;
    const int b   = blk & (BATCH - 1);

    // ---------------- stage ----------------
    {
        const float4* xg = (const float4*)(x + (size_t)(b*NELEC + s*NE) * DF);
        ((float4*)&sx[0][0])[t] = xg[t];
    }
    {
        const float4* wg = (const float4*)(W_orb + (size_t)s * 2*DF*NORB);
        float4* d = (float4*)&sworb[0][0];
        d[t]       = wg[t];
        d[t + 256] = wg[t + 256];
    }
    {
        const float4* rg = (const float4*)(r_ei + (size_t)(b*NELEC + s*NE) * NION * 3);
        float4* d = (float4*)&sr[0][0];
        d[t] = rg[t];
        if (t < 128) d[t + 256] = rg[t + 256];
    }
    {
        const float4* weg = (const float4*)(W_env + (size_t)s * NION*3*NORB*3);
        float4* d = (float4*)swe;
        for (int j = t; j < 1152; j += 256) d[j] = weg[j];
    }
    if (t < NORB) sb[t]    = b_orb[s*NORB + t];
    if (t < NION) swion[t] = w_ion[s*NION + t];
    __syncthreads();

    const int o  = t & 31;       // orbital across lanes -> conflict-free
    const int ng = t >> 5;       // electron group, 4 electrons each

    // ---------------- U, V (two 32x32x32 GEMMs) ----------------
    float u_acc[4], v_acc[4];
    #pragma unroll
    for (int uu = 0; uu < 4; ++uu) { u_acc[uu] = 0.f; v_acc[uu] = 0.f; }
    #pragma unroll
    for (int d = 0; d < DF; ++d) {
        const float w0 = sworb[d][o];
        const float w1 = sworb[DF + d][o];
        #pragma unroll
        for (int uu = 0; uu < 4; ++uu) {
            const float xv = sx[ng*4 + uu][d];
            u_acc[uu] += xv * w0;
            v_acc[uu] += xv * w1;
        }
    }

    // ---------------- envelope (ion-outer: 9 W reads amortized over 4 e-) ---
    float e_acc[4] = {0.f, 0.f, 0.f, 0.f};
    #pragma unroll
    for (int i = 0; i < NION; ++i) {
        // swe[((i*3+d)*NORB + o)*3 + e]; stride-3 across o, coprime 32 -> no conflict
        const float* wp = &swe[i*3*NORB*3 + o*3];
        const float w00 = wp[0],          w01 = wp[1],          w02 = wp[2];
        const float w10 = wp[NORB*3],     w11 = wp[NORB*3+1],   w12 = wp[NORB*3+2];
        const float w20 = wp[2*NORB*3],   w21 = wp[2*NORB*3+1], w22 = wp[2*NORB*3+2];
        const float wi  = swion[i];
        #pragma unroll
        for (int uu = 0; uu < 4; ++uu) {
            const int n = ng*4 + uu;
            const float r0 = sr[n][i*3 + 0];
            const float r1 = sr[n][i*3 + 1];
            const float r2 = sr[n][i*3 + 2];
            const float s0 = r0*w00 + r1*w10 + r2*w20;
            const float s1 = r0*w01 + r1*w11 + r2*w21;
            const float s2 = r0*w02 + r1*w12 + r2*w22;
            const float dist = sqrtf(s0*s0 + s1*s1 + s2*s2);
            e_acc[uu] += __expf(-dist) * wi;
        }
    }

    // ---------------- write factors (coalesced-ish: 2x128B segments/wave) ---
    const size_t base = (size_t)blk * (NE*NORB);
    #pragma unroll
    for (int uu = 0; uu < 4; ++uu) {
        const int n = ng*4 + uu;
        Uf[base + n*NORB + o] = u_acc[uu];
        Ef[base + n*NORB + o] = e_acc[uu];
        Wf[base + n*NORB + o] = (v_acc[uu] + sb[o]) * e_acc[uu];
    }
}

// ---------------------------------------------------------------------------
// K2: pure streaming expansion  out[p,i,o] = U[p,o]*E[i,o] + W[i,o]
// ---------------------------------------------------------------------------
__global__ __launch_bounds__(256) void k2_expand(
    const float* __restrict__ Uf,
    const float* __restrict__ Ef,
    const float* __restrict__ Wf,
    float* __restrict__ out)
{
    __shared__ float sU[NE][NORB];   // 4 KB
    const int t   = threadIdx.x;
    const int blk = blockIdx.x;
    const size_t base = (size_t)blk * (NE*NORB);

    ((float4*)&sU[0][0])[t] = ((const float4*)(Uf + base))[t];
    // thread t owns (i = t>>3, o0 = (t&7)*4); element offset = t*4 exactly
    const float4 e4 = ((const float4*)(Ef + base))[t];
    const float4 w4 = ((const float4*)(Wf + base))[t];
    __syncthreads();

    const int o0 = (t & 7) * 4;
    float4* outp = (float4*)(out + (size_t)blk * (NE*NE*NORB));
    #pragma unroll
    for (int p = 0; p < NE; ++p) {
        const float4 u4 = *(const float4*)&sU[p][o0];   // 8-way broadcast read
        float4 r;
        r.x = u4.x*e4.x + w4.x;
        r.y = u4.y*e4.y + w4.y;
        r.z = u4.z*e4.z + w4.z;
        r.w = u4.w*e4.w + w4.w;
        outp[p*256 + t] = r;   // 4 KB contiguous per iteration
    }
}

// ---------------------------------------------------------------------------
// Fallback: the proven single fused kernel (used only if ws is too small)
// ---------------------------------------------------------------------------
__global__ __launch_bounds__(256) void deq_orbital_fused(
    const float* __restrict__ x, const float* __restrict__ r_ei,
    const float* __restrict__ W_orb, const float* __restrict__ b_orb,
    const float* __restrict__ W_env, const float* __restrict__ w_ion,
    float* __restrict__ out)
{
    __shared__ float sx[NE][DF];
    __shared__ float sworb[2*DF][NORB];
    __shared__ float sr[NE][NION*3];
    __shared__ float swe[NION*3*NORB*3];
    __shared__ float sU[NE][NORB];
    __shared__ float sV[NE][NORB];
    __shared__ float sE[NE][NORB];
    __shared__ float sb[NORB];
    __shared__ float swion[NION];

    const int t   = threadIdx.x;
    const int blk = blockIdx.x;
    const int s   = blk >> 10;
    const int b   = blk & (BATCH - 1);

    {
        const float4* xg = (const float4*)(x + (size_t)(b*NELEC + s*NE) * DF);
        ((float4*)&sx[0][0])[t] = xg[t];
    }
    {
        const float4* wg = (const float4*)(W_orb + (size_t)s * 2*DF*NORB);
        float4* d = (float4*)&sworb[0][0];
        d[t] = wg[t]; d[t + 256] = wg[t + 256];
    }
    {
        const float4* rg = (const float4*)(r_ei + (size_t)(b*NELEC + s*NE) * NION * 3);
        float4* d = (float4*)&sr[0][0];
        d[t] = rg[t];
        if (t < 128) d[t + 256] = rg[t + 256];
    }
    {
        const float4* weg = (const float4*)(W_env + (size_t)s * NION*3*NORB*3);
        float4* d = (float4*)swe;
        for (int j = t; j < 1152; j += 256) d[j] = weg[j];
    }
    if (t < NORB) sb[t]    = b_orb[s*NORB + t];
    if (t < NION) swion[t] = w_ion[s*NION + t];
    __syncthreads();

    const int o  = t & 31;
    const int ng = t >> 5;
    float u_acc[4], v_acc[4];
    #pragma unroll
    for (int uu = 0; uu < 4; ++uu) { u_acc[uu] = 0.f; v_acc[uu] = 0.f; }
    #pragma unroll
    for (int d = 0; d < DF; ++d) {
        const float w0 = sworb[d][o];
        const float w1 = sworb[DF + d][o];
        #pragma unroll
        for (int uu = 0; uu < 4; ++uu) {
            const float xv = sx[ng*4 + uu][d];
            u_acc[uu] += xv * w0;
            v_acc[uu] += xv * w1;
        }
    }
    #pragma unroll
    for (int uu = 0; uu < 4; ++uu) {
        sU[ng*4 + uu][o] = u_acc[uu];
        sV[ng*4 + uu][o] = v_acc[uu];
    }
    #pragma unroll
    for (int uu = 0; uu < 4; ++uu) {
        const int n = ng*4 + uu;
        float acc = 0.f;
        #pragma unroll
        for (int i = 0; i < NION; ++i) {
            const float r0 = sr[n][i*3 + 0];
            const float r1 = sr[n][i*3 + 1];
            const float r2 = sr[n][i*3 + 2];
            const float* wp = &swe[i*3*NORB*3 + o*3];
            const float s0 = r0*wp[0] + r1*wp[NORB*3    ] + r2*wp[2*NORB*3    ];
            const float s1 = r0*wp[1] + r1*wp[NORB*3 + 1] + r2*wp[2*NORB*3 + 1];
            const float s2 = r0*wp[2] + r1*wp[NORB*3 + 2] + r2*wp[2*NORB*3 + 2];
            const float dist = sqrtf(s0*s0 + s1*s1 + s2*s2);
            acc += __expf(-dist) * swion[i];
        }
        sE[n][o] = acc;
        sV[n][o] = (v_acc[uu] + sb[o]) * acc;
    }
    __syncthreads();

    const int io = t >> 3;
    const int o0 = (t & 7) * 4;
    const float4 e4 = *(const float4*)&sE[io][o0];
    const float4 w4 = *(const float4*)&sV[io][o0];
    float4* outp = (float4*)(out + (size_t)blk * (NE*NE*NORB));
    #pragma unroll
    for (int p = 0; p < NE; ++p) {
        const float4 u4 = *(const float4*)&sU[p][o0];
        float4 r;
        r.x = u4.x*e4.x + w4.x;
        r.y = u4.y*e4.y + w4.y;
        r.z = u4.z*e4.z + w4.z;
        r.w = u4.w*e4.w + w4.w;
        outp[p*256 + t] = r;
    }
}

extern "C" void kernel_launch(void* const* d_in, const int* in_sizes, int n_in,
                              void* d_out, int out_size, void* d_ws, size_t ws_size,
                              hipStream_t stream) {
    const float* x     = (const float*)d_in[0];
    const float* r_ei  = (const float*)d_in[1];
    const float* W_orb = (const float*)d_in[2];
    const float* b_orb = (const float*)d_in[3];
    const float* W_env = (const float*)d_in[4];
    const float* w_ion = (const float*)d_in[5];
    float* out = (float*)d_out;

    if (ws_size >= WS_NEEDED) {
        float* Uf = (float*)d_ws;
        float* Ef = Uf + FACT_FLOATS;
        float* Wf = Ef + FACT_FLOATS;
        k1_factors<<<NSB, 256, 0, stream>>>(x, r_ei, W_orb, b_orb, W_env, w_ion,
                                            Uf, Ef, Wf);
        k2_expand<<<NSB, 256, 0, stream>>>(Uf, Ef, Wf, out);
    } else {
        deq_orbital_fused<<<NSB, 256, 0, stream>>>(x, r_ei, W_orb, b_orb,
                                                   W_env, w_ion, out);
    }
}